// Round 3
// baseline (1393.622 us; speedup 1.0000x reference)
//
#include <hip/hip_runtime.h>
#include <hip/hip_bf16.h>
#include <stdint.h>

// ChunkedLocalAttention on MI355X (gfx950).
// R3: workspace-adaptive (R2's fixed 528 MiB demand is the prime crash suspect —
// GPU page fault aborts exactly as observed). Now:
//   - QKV GEMMs read x fp32 directly, split to bf16 hi/lo IN-REGISTER while
//     staging A to LDS (B = pre-transposed split weights via global_load_lds).
//   - Q/K/V fp32 exist only per-slice of R rows (R picked from ws_size, 8192 pref).
//   - attn output = split bf16 (128 MiB), final GEMM = m97-style split GEMM.
// Split-bf16 GEMM: A*B ~= Ahi*Bhi + Ahi*Blo + Alo*Bhi  (~1.5e-5 rel err).
// Workspace: 144 MiB + 12*R KiB (240 MiB at R=8192; min 147 MiB; 83 MiB fallback).

#define DEV __device__ __forceinline__

typedef __attribute__((ext_vector_type(8))) short short8;
typedef __attribute__((ext_vector_type(4))) float f32x4;

// async global->LDS, 16B/lane; LDS dest = wave-uniform base + lane*16 (m104).
#define GLOAD16(g, l)                                              \
  __builtin_amdgcn_global_load_lds(                                \
      (const __attribute__((address_space(1))) void*)(g),          \
      (__attribute__((address_space(3))) void*)(l), 16, 0, 0)

DEV unsigned short f2bf(float f) {              // RNE float->bf16
  unsigned int u = __float_as_uint(f);
  u += 0x7FFFu + ((u >> 16) & 1u);
  return (unsigned short)(u >> 16);
}
DEV float bf2f(unsigned short u) { return __uint_as_float(((unsigned int)u) << 16); }

DEV void cvt8(const float4& a, const float4& b, short8& hv, short8& lv) {
  float f[8] = {a.x, a.y, a.z, a.w, b.x, b.y, b.z, b.w};
#pragma unroll
  for (int e = 0; e < 8; ++e) {
    unsigned short h = f2bf(f[e]);
    hv[e] = (short)h;
    lv[e] = (short)f2bf(f[e] - bf2f(h));
  }
}

// ------------------------------------------- transpose + split weights (KxN -> NxK)
__global__ void k_transpose_split(const float* __restrict__ W,
                                  unsigned short* __restrict__ Thi,
                                  unsigned short* __restrict__ Tlo) {
  __shared__ float t[64][65];
  const int bx = blockIdx.x * 64;                   // n tile
  const int by = blockIdx.y * 64;                   // k tile
  const int tx = threadIdx.x & 63;
  const int ty = threadIdx.x >> 6;
#pragma unroll
  for (int p = 0; p < 16; ++p) {
    int r = p * 4 + ty;
    t[r][tx] = W[(size_t)(by + r) * 1024 + bx + tx];
  }
  __syncthreads();
#pragma unroll
  for (int p = 0; p < 16; ++p) {
    int r = p * 4 + ty;
    float f = t[tx][r];                             // = W[by+tx][bx+r]
    unsigned short h = f2bf(f);
    size_t o = (size_t)(bx + r) * 1024 + by + tx;   // Wt[n][k]
    Thi[o] = h;
    Tlo[o] = f2bf(f - bf2f(h));
  }
}

// -------------------------------------------------- QKV GEMM: fp32 A, split B
// C[slice rows x 1024] = X[row0+...][1024] * (Bhi+Blo)^T  (B pre-transposed NxK).
// 128x128 tile, BK=32, 4 waves. A: reg-staged fp32 -> in-register hi/lo split ->
// ds_write_b128. B: global_load_lds 16B/lane. MFMA 16x16x32 bf16, 3 terms.
// C/D layout (m89): col = lane&15, row = (lane>>4)*4 + reg.
__global__ void k_gemm_xsplit(const float* __restrict__ X,
                              const unsigned short* __restrict__ Bhi,
                              const unsigned short* __restrict__ Blo,
                              float* __restrict__ C, int row0) {
  const int Kd = 1024, Nd = 1024;
  __shared__ unsigned short sAh[128 * 32], sAl[128 * 32], sBh[128 * 32], sBl[128 * 32];
  const int tid = threadIdx.x, lane = tid & 63, wv = tid >> 6;
  const int wm = wv >> 1, wn = wv & 1, r = lane & 15, g = lane >> 4;

  // XCD-aware swizzle; nwg = 8*mtiles, always %8==0 here.
  const int nwg = gridDim.x, cpx = nwg >> 3;
  const int swz = (blockIdx.x & 7) * cpx + (blockIdx.x >> 3);
  const int n0 = (swz & 7) * 128, m0 = (swz >> 3) * 128;

  const int srow = tid >> 2, seg = tid & 3;
  const float* x0 = X + (size_t)(row0 + m0 + srow) * Kd + seg * 8;
  const float* x1 = x0 + (size_t)64 * Kd;
  const int as0 = srow * 32 + seg * 8, as1 = as0 + 64 * 32;

  const int brow = wv * 32 + (lane >> 2);
  const size_t gB = (size_t)(n0 + brow) * Kd + (lane & 3) * 8;
  const int o0 = wv * 1024, o1 = o0 + 512;          // wave-uniform LDS elem offsets

  f32x4 acc[4][4] = {};

  for (int kt = 0; kt < Kd; kt += 32) {
    float4 a00 = *(const float4*)(x0 + kt);
    float4 a01 = *(const float4*)(x0 + kt + 4);
    float4 a10 = *(const float4*)(x1 + kt);
    float4 a11 = *(const float4*)(x1 + kt + 4);
    __syncthreads();                                // prev tile's readers done
    GLOAD16(Bhi + gB + kt, sBh + o0);
    GLOAD16(Bhi + gB + kt + (size_t)16 * Kd, sBh + o1);
    GLOAD16(Blo + gB + kt, sBl + o0);
    GLOAD16(Blo + gB + kt + (size_t)16 * Kd, sBl + o1);
    short8 h0, l0, h1, l1;
    cvt8(a00, a01, h0, l0);
    cvt8(a10, a11, h1, l1);
    *(short8*)(sAh + as0) = h0; *(short8*)(sAl + as0) = l0;
    *(short8*)(sAh + as1) = h1; *(short8*)(sAl + as1) = l1;
    __syncthreads();                                // vmcnt+lgkmcnt drained

    short8 ah[4], al[4], bh[4], bl[4];
#pragma unroll
    for (int i = 0; i < 4; ++i) {
      ah[i] = *(const short8*)(sAh + (wm * 64 + i * 16 + r) * 32 + g * 8);
      al[i] = *(const short8*)(sAl + (wm * 64 + i * 16 + r) * 32 + g * 8);
      bh[i] = *(const short8*)(sBh + (wn * 64 + i * 16 + r) * 32 + g * 8);
      bl[i] = *(const short8*)(sBl + (wn * 64 + i * 16 + r) * 32 + g * 8);
    }
#pragma unroll
    for (int i = 0; i < 4; ++i)
#pragma unroll
      for (int j = 0; j < 4; ++j) {
        acc[i][j] = __builtin_amdgcn_mfma_f32_16x16x32_bf16(ah[i], bh[j], acc[i][j], 0, 0, 0);
        acc[i][j] = __builtin_amdgcn_mfma_f32_16x16x32_bf16(ah[i], bl[j], acc[i][j], 0, 0, 0);
        acc[i][j] = __builtin_amdgcn_mfma_f32_16x16x32_bf16(al[i], bh[j], acc[i][j], 0, 0, 0);
      }
  }

#pragma unroll
  for (int i = 0; i < 4; ++i)
#pragma unroll
    for (int j = 0; j < 4; ++j) {
      int row = m0 + wm * 64 + i * 16 + g * 4;      // slice-local
      int col = n0 + wn * 64 + j * 16 + r;
#pragma unroll
      for (int e = 0; e < 4; ++e)
        C[(size_t)(row + e) * Nd + col] = acc[i][j][e];
    }
}

// ---------------------------------------------- final GEMM: split A, split B
// A (attn-out) already bf16 hi/lo -> full global_load_lds staging (m97 pattern).
// LO=0: skip A-lo term (low-memory fallback).
template <int LO>
__global__ void k_gemm_final(const unsigned short* __restrict__ Ahi,
                             const unsigned short* __restrict__ Alo,
                             const unsigned short* __restrict__ Bhi,
                             const unsigned short* __restrict__ Blo,
                             float* __restrict__ C) {
  const int Kd = 1024, Nd = 1024;
  __shared__ unsigned short sAh[128 * 32], sAl[128 * 32], sBh[128 * 32], sBl[128 * 32];
  const int tid = threadIdx.x, lane = tid & 63, wv = tid >> 6;
  const int wm = wv >> 1, wn = wv & 1, r = lane & 15, g = lane >> 4;

  const int nwg = gridDim.x, cpx = nwg >> 3;        // 2048, %8==0
  const int swz = (blockIdx.x & 7) * cpx + (blockIdx.x >> 3);
  const int n0 = (swz & 7) * 128, m0 = (swz >> 3) * 128;

  const int srow = wv * 32 + (lane >> 2);
  const int seg = lane & 3;
  const size_t gA = (size_t)(m0 + srow) * Kd + seg * 8;
  const size_t gB = (size_t)(n0 + srow) * Kd + seg * 8;
  const int o0 = wv * 1024, o1 = o0 + 512;

  f32x4 acc[4][4] = {};

  for (int kt = 0; kt < Kd; kt += 32) {
    __syncthreads();
    GLOAD16(Ahi + gA + kt, sAh + o0);
    GLOAD16(Ahi + gA + kt + (size_t)16 * Kd, sAh + o1);
    if (LO) {
      GLOAD16(Alo + gA + kt, sAl + o0);
      GLOAD16(Alo + gA + kt + (size_t)16 * Kd, sAl + o1);
    }
    GLOAD16(Bhi + gB + kt, sBh + o0);
    GLOAD16(Bhi + gB + kt + (size_t)16 * Kd, sBh + o1);
    GLOAD16(Blo + gB + kt, sBl + o0);
    GLOAD16(Blo + gB + kt + (size_t)16 * Kd, sBl + o1);
    __syncthreads();

    short8 ah[4], al[4], bh[4], bl[4];
#pragma unroll
    for (int i = 0; i < 4; ++i) {
      ah[i] = *(const short8*)(sAh + (wm * 64 + i * 16 + r) * 32 + g * 8);
      if (LO) al[i] = *(const short8*)(sAl + (wm * 64 + i * 16 + r) * 32 + g * 8);
      bh[i] = *(const short8*)(sBh + (wn * 64 + i * 16 + r) * 32 + g * 8);
      bl[i] = *(const short8*)(sBl + (wn * 64 + i * 16 + r) * 32 + g * 8);
    }
#pragma unroll
    for (int i = 0; i < 4; ++i)
#pragma unroll
      for (int j = 0; j < 4; ++j) {
        acc[i][j] = __builtin_amdgcn_mfma_f32_16x16x32_bf16(ah[i], bh[j], acc[i][j], 0, 0, 0);
        acc[i][j] = __builtin_amdgcn_mfma_f32_16x16x32_bf16(ah[i], bl[j], acc[i][j], 0, 0, 0);
        if (LO)
          acc[i][j] = __builtin_amdgcn_mfma_f32_16x16x32_bf16(al[i], bh[j], acc[i][j], 0, 0, 0);
      }
  }

#pragma unroll
  for (int i = 0; i < 4; ++i)
#pragma unroll
    for (int j = 0; j < 4; ++j) {
      int row = m0 + wm * 64 + i * 16 + g * 4;
      int col = n0 + wn * 64 + j * 16 + r;
#pragma unroll
      for (int e = 0; e < 4; ++e)
        C[(size_t)(row + e) * Nd + col] = acc[i][j][e];
    }
}

// ---------------------------------------------------------------- attention
// Slice version: q/k/v are slice-local (R rows); output at absolute rows.
// One block = 64 query rows of one (chunk, head). 4 lanes/row, 16 dims each;
// dot combined via shfl_xor(1),shfl_xor(2). K,V fp32 in LDS [128][68].
// Softmax w/o max subtraction (|s| <~ 7, safe in fp32; diagonal always valid
// so lsum >= exp(s_ii) > 0).
__global__ __launch_bounds__(256, 2)
void k_attn(const float* __restrict__ q, const float* __restrict__ k,
            const float* __restrict__ v,
            unsigned short* __restrict__ ohi, unsigned short* __restrict__ olo,
            int row0, int wlo) {
  const int h  = blockIdx.x >> 2;
  const int rb = blockIdx.x & 3;
  const int cy = blockIdx.y;                        // chunk within slice
  const int r0 = rb * 64;                           // chunk-relative first row
  const int tid = threadIdx.x;
  const int m  = tid >> 2;
  const int qd = tid & 3;

  __shared__ float sK[128 * 68];
  __shared__ float sV[128 * 68];

  const size_t cbase = (size_t)(cy * 256) * 1024 + h * 64;          // slice-local

  for (int it = 0; it < 8; ++it) {
    int idx = tid + it * 256;
    int slot = idx >> 4;
    int seg  = idx & 15;
    int gr = r0 - 64 + slot;                        // chunk-relative
    float4 kv4 = make_float4(0.f, 0.f, 0.f, 0.f);
    float4 vv4 = make_float4(0.f, 0.f, 0.f, 0.f);
    if (gr >= 0) {
      size_t go = cbase + (size_t)gr * 1024 + seg * 4;
      kv4 = *(const float4*)(k + go);
      vv4 = *(const float4*)(v + go);
    }
    *(float4*)(sK + slot * 68 + seg * 4) = kv4;
    *(float4*)(sV + slot * 68 + seg * 4) = vv4;
  }

  const int i = r0 + m;
  float qreg[16];
  {
    size_t go = cbase + (size_t)i * 1024 + qd * 16;
#pragma unroll
    for (int s = 0; s < 4; ++s) {
      float4 f = *(const float4*)(q + go + s * 4);
      qreg[s * 4 + 0] = f.x; qreg[s * 4 + 1] = f.y;
      qreg[s * 4 + 2] = f.z; qreg[s * 4 + 3] = f.w;
    }
  }
  __syncthreads();

  float acc[16];
#pragma unroll
  for (int d = 0; d < 16; ++d) acc[d] = 0.f;
  float lsum = 0.f;

  for (int jj = 0; jj <= 64; ++jj) {
    int slot = m + jj;
    bool valid = (i - 64 + jj) >= 0;
    float p0 = 0.f, p1 = 0.f, p2 = 0.f, p3 = 0.f;
    const float* kr = sK + slot * 68 + qd * 16;
#pragma unroll
    for (int s = 0; s < 4; ++s) {
      float4 f = *(const float4*)(kr + s * 4);
      p0 += qreg[s * 4 + 0] * f.x; p1 += qreg[s * 4 + 1] * f.y;
      p2 += qreg[s * 4 + 2] * f.z; p3 += qreg[s * 4 + 3] * f.w;
    }
    float part = (p0 + p1) + (p2 + p3);
    part += __shfl_xor(part, 1);
    part += __shfl_xor(part, 2);
    float pexp = valid ? __expf(part * 0.125f) : 0.f;
    lsum += pexp;
    const float* vr = sV + slot * 68 + qd * 16;
#pragma unroll
    for (int s = 0; s < 4; ++s) {
      float4 f = *(const float4*)(vr + s * 4);
      acc[s * 4 + 0] += pexp * f.x; acc[s * 4 + 1] += pexp * f.y;
      acc[s * 4 + 2] += pexp * f.z; acc[s * 4 + 3] += pexp * f.w;
    }
  }

  float inv = 1.f / lsum;
  size_t go = ((size_t)row0 + cy * 256 + i) * 1024 + h * 64 + qd * 16;  // absolute
#pragma unroll
  for (int s = 0; s < 4; ++s) {
    float o0 = acc[s * 4 + 0] * inv, o1 = acc[s * 4 + 1] * inv;
    float o2 = acc[s * 4 + 2] * inv, o3 = acc[s * 4 + 3] * inv;
    ushort4 hv, lv;
    hv.x = f2bf(o0); lv.x = f2bf(o0 - bf2f(hv.x));
    hv.y = f2bf(o1); lv.y = f2bf(o1 - bf2f(hv.y));
    hv.z = f2bf(o2); lv.z = f2bf(o2 - bf2f(hv.z));
    hv.w = f2bf(o3); lv.w = f2bf(o3 - bf2f(hv.w));
    *(ushort4*)(ohi + go + s * 4) = hv;
    if (wlo) *(ushort4*)(olo + go + s * 4) = lv;
  }
}

// ---------------------------------------------------------------- launcher
extern "C" void kernel_launch(void* const* d_in, const int* in_sizes, int n_in,
                              void* d_out, int out_size, void* d_ws, size_t ws_size,
                              hipStream_t stream) {
  const float* x  = (const float*)d_in[0];
  const float* Wq = (const float*)d_in[1];
  const float* Wk = (const float*)d_in[2];
  const float* Wv = (const float*)d_in[3];
  const float* Wo = (const float*)d_in[4];
  float* out = (float*)d_out;

  const int M = 32768;
  const size_t MiB = (size_t)1 << 20;

  // pick slice rows R and whether we can afford the A-lo channel of attn-out
  int R = 0;
  bool lo = true;
  const int cands[6] = {8192, 4096, 2048, 1024, 512, 256};
  for (int c : cands)
    if (144 * MiB + (size_t)c * 12288 <= ws_size) { R = c; break; }
  if (!R) {
    lo = false;
    for (int c : cands)
      if (80 * MiB + (size_t)c * 12288 <= ws_size) { R = c; break; }
    if (!R) R = 256;  // last resort; nothing smaller is possible
  }

  // ws layout: wt (16 MiB) | aoh (64 MiB) | [aol (64 MiB) if lo] | q|k|v slices
  char* ws = (char*)d_ws;
  unsigned short* wt  = (unsigned short*)ws;
  unsigned short* aoh = (unsigned short*)(ws + 16 * MiB);
  unsigned short* aol = lo ? (unsigned short*)(ws + 80 * MiB) : aoh;
  char* sl = ws + (lo ? 144 : 80) * MiB;
  float* qs = (float*)sl;
  float* ks = (float*)(sl + (size_t)R * 4096);
  float* vs = (float*)(sl + (size_t)R * 8192);

  dim3 tg(16, 16);
  k_transpose_split<<<tg, 256, 0, stream>>>(Wq, wt + 0 * 1048576, wt + 1 * 1048576);
  k_transpose_split<<<tg, 256, 0, stream>>>(Wk, wt + 2 * 1048576, wt + 3 * 1048576);
  k_transpose_split<<<tg, 256, 0, stream>>>(Wv, wt + 4 * 1048576, wt + 5 * 1048576);
  k_transpose_split<<<tg, 256, 0, stream>>>(Wo, wt + 6 * 1048576, wt + 7 * 1048576);

  const int qkv_grid = 8 * (R / 128);               // %8==0 for all R choices
  const dim3 ag(64, R / 256);
  const int nslices = M / R;
  for (int s = 0; s < nslices; ++s) {
    const int row0 = s * R;
    k_gemm_xsplit<<<qkv_grid, 256, 0, stream>>>(x, wt + 0 * 1048576, wt + 1 * 1048576, qs, row0);
    k_gemm_xsplit<<<qkv_grid, 256, 0, stream>>>(x, wt + 2 * 1048576, wt + 3 * 1048576, ks, row0);
    k_gemm_xsplit<<<qkv_grid, 256, 0, stream>>>(x, wt + 4 * 1048576, wt + 5 * 1048576, vs, row0);
    k_attn<<<ag, 256, 0, stream>>>(qs, ks, vs, aoh, aol, row0, lo ? 1 : 0);
  }

  const int fin_grid = 8 * (M / 128);               // 2048
  if (lo)
    k_gemm_final<1><<<fin_grid, 256, 0, stream>>>(aoh, aol, wt + 6 * 1048576, wt + 7 * 1048576, out);
  else
    k_gemm_final<0><<<fin_grid, 256, 0, stream>>>(aoh, aol, wt + 6 * 1048576, wt + 7 * 1048576, out);
}